// Round 1
// baseline (3755.247 us; speedup 1.0000x reference)
//
#include <hip/hip_runtime.h>
#include <math.h>
#include <float.h>

#define BATCH 4
#define CH    256
#define NT    4096
#define NCTX  8192
#define KI    8
#define CAND  16
#define NSPLIT 4

// ---------------- transpose: channel-major [CH][M] -> node-major [M][CH] ----------------
__global__ __launch_bounds__(256) void k_transpose(const float* __restrict__ src,
                                                   float* __restrict__ dst,
                                                   int M, long srcBatch, long dstBatch) {
  __shared__ float tile[32][33];
  const float* s = src + (long)blockIdx.z * srcBatch;
  float* d = dst + (long)blockIdx.z * dstBatch;
  const int m0 = blockIdx.x * 32, c0 = blockIdx.y * 32;
  const int tx = threadIdx.x, ty = threadIdx.y;
#pragma unroll
  for (int i = ty; i < 32; i += 8)
    tile[i][tx] = s[(long)(c0 + i) * M + (m0 + tx)];
  __syncthreads();
#pragma unroll
  for (int i = ty; i < 32; i += 8)
    d[(long)(m0 + i) * CH + (c0 + tx)] = tile[tx][i];
}

// ---------------- context squared norms (fp32, coarse ranking only) ----------------
__global__ __launch_bounds__(256) void k_norms(const float* __restrict__ xc1,
                                               const float* __restrict__ xc2,
                                               float* __restrict__ nrm) {
  const int j = blockIdx.x * 256 + threadIdx.x;
  const int b = blockIdx.y;
  const float* src = (j < NT) ? (xc1 + (long)b * CH * NT + j)
                              : (xc2 + (long)b * CH * NT + (j - NT));
  float acc = 0.f;
#pragma unroll 8
  for (int c = 0; c < CH; ++c) {
    float v = src[(long)c * NT];
    acc = fmaf(v, v, acc);
  }
  nrm[(long)b * NCTX + j] = acc;
}

// ---------------- fused distance GEMM + per-target top-16 (per context split) ----------------
#define TMD 64
#define TND 64
#define KCD 64
__global__ __launch_bounds__(256) void k_dist_topk(const float* __restrict__ Xt,
                                                   const float* __restrict__ Xc1,
                                                   const float* __restrict__ Xc2,
                                                   const float* __restrict__ nrm,
                                                   int* __restrict__ cand) {
  __shared__ float As[KCD][TMD];       // 16 KB
  __shared__ float Bs[KCD][TND];       // 16 KB
  __shared__ float Ss[TMD][TND + 4];   // 17.4 KB (pad 4 keeps float4 alignment)
  const int b = blockIdx.y;
  const int i0 = blockIdx.x * TMD;
  const int split = blockIdx.z;
  const float* A = Xt + (long)b * CH * NT;
  const int t = threadIdx.x;
  const int tm = (t & 15) * 4;
  const int tn = (t >> 4) * 4;

  float bd[CAND];
  int   bi[CAND];
#pragma unroll
  for (int q = 0; q < CAND; ++q) { bd[q] = FLT_MAX; bi[q] = 0x7fffffff; }

  const int jt0 = split * (NCTX / TND / NSPLIT);
  const int jt1 = jt0 + (NCTX / TND / NSPLIT);
  for (int jt = jt0; jt < jt1; ++jt) {
    const int j0 = jt * TND;
    const float* Bp = (j0 < NT) ? (Xc1 + (long)b * CH * NT + j0)
                                : (Xc2 + (long)b * CH * NT + (j0 - NT));
    float acc[4][4] = {{0.f}};
    for (int kc = 0; kc < CH; kc += KCD) {
      __syncthreads();
#pragma unroll
      for (int rep = 0; rep < 4; ++rep) {
        int p = t + rep * 256;
        int row = p >> 4;
        int col = (p & 15) * 4;
        *(float4*)&As[row][col] = *(const float4*)(A  + (long)(kc + row) * NT + i0 + col);
        *(float4*)&Bs[row][col] = *(const float4*)(Bp + (long)(kc + row) * NT + col);
      }
      __syncthreads();
#pragma unroll 8
      for (int k = 0; k < KCD; ++k) {
        float av[4], bv[4];
        *(float4*)av = *(const float4*)&As[k][tm];
        *(float4*)bv = *(const float4*)&Bs[k][tn];
#pragma unroll
        for (int r = 0; r < 4; ++r)
#pragma unroll
          for (int c2 = 0; c2 < 4; ++c2)
            acc[r][c2] = fmaf(av[r], bv[c2], acc[r][c2]);
      }
    }
    __syncthreads();
    // coarse score s = |xc|^2 - 2*dot  (|xt|^2 is a per-row constant; ranking unaffected)
    float nv[4];
#pragma unroll
    for (int c2 = 0; c2 < 4; ++c2) nv[c2] = nrm[(long)b * NCTX + j0 + tn + c2];
#pragma unroll
    for (int r = 0; r < 4; ++r) {
      float4 sv;
      sv.x = nv[0] - 2.f * acc[r][0];
      sv.y = nv[1] - 2.f * acc[r][1];
      sv.z = nv[2] - 2.f * acc[r][2];
      sv.w = nv[3] - 2.f * acc[r][3];
      *(float4*)&Ss[tm + r][tn] = sv;
    }
    __syncthreads();
    if (t < TMD) {
      float worst = bd[CAND - 1];
      for (int jj = 0; jj < TND; ++jj) {
        float s = Ss[t][jj];
        if (s < worst) {                    // strict: ties keep earlier (smaller) index
          int j = j0 + jj;
          // branchless sorted insert — all indices static -> stays in registers
#pragma unroll
          for (int q = 0; q < CAND; ++q) {
            bool lt = (s < bd[q]);
            float od = bd[q]; int oi = bi[q];
            if (lt) { bd[q] = s; bi[q] = j; s = od; j = oi; }
          }
          worst = bd[CAND - 1];
        }
      }
    }
  }
  if (t < TMD) {
    long base = (((long)b * NT + i0 + t) * NSPLIT + split) * CAND;
#pragma unroll
    for (int q = 0; q < CAND; ++q) cand[base + q] = bi[q];
  }
}

// ---------------- fp64 exact rescore of 64 candidates -> knn[8] ----------------
__global__ __launch_bounds__(64) void k_rescore(const float* __restrict__ XtT,
                                                const float* __restrict__ XcT,
                                                const int* __restrict__ cand,
                                                int* __restrict__ knn) {
  const int n = blockIdx.x, b = blockIdx.y, lane = threadIdx.x;
  __shared__ double sd[NSPLIT * CAND];
  __shared__ int    sj[NSPLIT * CAND];
  const float* xt = XtT + ((long)b * NT + n) * CH;
  float4 xa = *(const float4*)(xt + lane * 4);
  const int* cd = cand + ((long)b * NT + n) * (NSPLIT * CAND);
  for (int q = 0; q < NSPLIT * CAND; ++q) {
    int j = cd[q];
    const float* xc = XcT + ((long)b * NCTX + j) * CH;
    float4 xb = *(const float4*)(xc + lane * 4);
    double d0 = (double)xa.x - (double)xb.x;
    double acc = d0 * d0;
    double d1 = (double)xa.y - (double)xb.y; acc += d1 * d1;
    double d2 = (double)xa.z - (double)xb.z; acc += d2 * d2;
    double d3 = (double)xa.w - (double)xb.w; acc += d3 * d3;
#pragma unroll
    for (int off = 32; off > 0; off >>= 1) acc += __shfl_down(acc, off);
    if (lane == 0) { sd[q] = acc; sj[q] = j; }
  }
  __syncthreads();
  if (lane == 0) {
    unsigned long long used = 0ull;
    long obase = ((long)b * NT + n) * KI;
    for (int r = 0; r < KI; ++r) {
      double best = DBL_MAX; int bj = 0x7fffffff; int bq = 0;
      for (int q = 0; q < NSPLIT * CAND; ++q) {
        if (used & (1ull << q)) continue;
        double d = sd[q]; int j = sj[q];
        if (d < best || (d == best && j < bj)) { best = d; bj = j; bq = q; }
      }
      used |= (1ull << bq);
      knn[obase + r] = bj;
    }
  }
}

// ---------------- counts (segment_sum of ones) ----------------
__global__ __launch_bounds__(256) void k_counts(const int* __restrict__ knn,
                                                unsigned* __restrict__ counts) {
  const int idx = blockIdx.x * 256 + threadIdx.x;   // over BATCH*NT
  const int b = idx >> 12;                          // NT = 4096
  const int* kn = knn + (long)idx * KI;
#pragma unroll
  for (int q = 0; q < KI; ++q) atomicAdd(&counts[(long)b * NCTX + kn[q]], 1u);
}

// ---------------- GEMM + bias: out[M][CH] = A[M][CH] @ W[CH][CH] + b ----------------
#define GTM 64
#define GTN 64
#define GKC 32
__global__ __launch_bounds__(256) void k_gemm_bias(const float* __restrict__ A,
                                                   const float* __restrict__ Wm,
                                                   const float* __restrict__ bias,
                                                   float* __restrict__ out, int M) {
  __shared__ float As[GKC][GTM + 4];
  __shared__ float Bs[GKC][GTN];
  const int b = blockIdx.z;
  const long m0 = (long)blockIdx.x * GTM;
  const int n0 = blockIdx.y * GTN;
  const float* Ab = A + (long)b * M * CH;
  float* ob = out + (long)b * M * CH;
  const int t = threadIdx.x;
  const int tm = (t & 15) * 4;
  const int tn = (t >> 4) * 4;
  float acc[4][4] = {{0.f}};
  for (int kc = 0; kc < CH; kc += GKC) {
    __syncthreads();
#pragma unroll
    for (int rep = 0; rep < 2; ++rep) {
      int p = t + rep * 256;
      // A tile: [64 m][32 k], transpose into LDS
      int row = p >> 3;
      int ck = (p & 7) * 4;
      float4 va = *(const float4*)(Ab + (m0 + row) * CH + kc + ck);
      As[ck + 0][row] = va.x;
      As[ck + 1][row] = va.y;
      As[ck + 2][row] = va.z;
      As[ck + 3][row] = va.w;
      // B tile: [32 k][64 n], direct
      int rowb = p >> 4;
      int cn = (p & 15) * 4;
      *(float4*)&Bs[rowb][cn] = *(const float4*)(Wm + (long)(kc + rowb) * CH + n0 + cn);
    }
    __syncthreads();
#pragma unroll 8
    for (int k = 0; k < GKC; ++k) {
      float av[4], bv[4];
      *(float4*)av = *(const float4*)&As[k][tm];
      *(float4*)bv = *(const float4*)&Bs[k][tn];
#pragma unroll
      for (int r = 0; r < 4; ++r)
#pragma unroll
        for (int c2 = 0; c2 < 4; ++c2)
          acc[r][c2] = fmaf(av[r], bv[c2], acc[r][c2]);
    }
  }
#pragma unroll
  for (int r = 0; r < 4; ++r) {
    float4 ov;
    ov.x = acc[r][0] + bias[n0 + tn + 0];
    ov.y = acc[r][1] + bias[n0 + tn + 1];
    ov.z = acc[r][2] + bias[n0 + tn + 2];
    ov.w = acc[r][3] + bias[n0 + tn + 3];
    *(float4*)(ob + (m0 + tm + r) * CH + n0 + tn) = ov;
  }
}

// ---------------- gather-mean: X_edge = (Xn_t + sum_k Xn_c[knn]) / 9 ----------------
__global__ __launch_bounds__(256) void k_gather(const float* __restrict__ Xn_t,
                                                const float* __restrict__ Xn_c,
                                                const int* __restrict__ knn,
                                                float* __restrict__ Xe) {
  const int n = blockIdx.x, b = blockIdx.y, c = threadIdx.x;
  const int* kn = knn + ((long)b * NT + n) * KI;
  int j[KI];
#pragma unroll
  for (int q = 0; q < KI; ++q) j[q] = kn[q];
  float acc = Xn_t[((long)b * NT + n) * CH + c];
#pragma unroll
  for (int q = 0; q < KI; ++q) acc += Xn_c[((long)b * NCTX + j[q]) * CH + c];
  Xe[((long)b * NT + n) * CH + c] = acc / 9.0f;
}

// ---------------- scatter-add contributions to context nodes ----------------
__global__ __launch_bounds__(256) void k_scatter(const float* __restrict__ Xet,
                                                 const int* __restrict__ knn,
                                                 float* __restrict__ contrib) {
  const int n = blockIdx.x, b = blockIdx.y, c = threadIdx.x;
  const float v = Xet[((long)b * NT + n) * CH + c];
  const int* kn = knn + ((long)b * NT + n) * KI;
#pragma unroll
  for (int q = 0; q < KI; ++q)
    atomicAdd(&contrib[((long)b * NCTX + kn[q]) * CH + c], v);
}

// ---------------- finalize target output: transpose [NT][CH] -> image [CH][NT] ----------------
__global__ __launch_bounds__(256) void k_fin_t(const float* __restrict__ Xet,
                                               float* __restrict__ out) {
  __shared__ float tile[32][33];
  const int b = blockIdx.z;
  const int n0 = blockIdx.x * 32, c0 = blockIdx.y * 32;
  const int tx = threadIdx.x, ty = threadIdx.y;
#pragma unroll
  for (int i = ty; i < 32; i += 8)
    tile[i][tx] = Xet[((long)b * NT + n0 + i) * CH + c0 + tx];
  __syncthreads();
#pragma unroll
  for (int i = ty; i < 32; i += 8)
    out[((long)b * CH + c0 + i) * NT + n0 + tx] = tile[tx][i];
}

// ---------------- finalize context outputs: divide by counts, transpose, split ----------------
__global__ __launch_bounds__(256) void k_fin_c(const float* __restrict__ contrib,
                                               const unsigned* __restrict__ counts,
                                               float* __restrict__ out1,
                                               float* __restrict__ out2) {
  __shared__ float tile[32][33];
  const int b = blockIdx.z;
  const int j0 = blockIdx.x * 32, c0 = blockIdx.y * 32;
  const int tx = threadIdx.x, ty = threadIdx.y;
#pragma unroll
  for (int i = ty; i < 32; i += 8) {
    float cnt = fmaxf((float)counts[(long)b * NCTX + j0 + i], 1.0f);
    tile[i][tx] = contrib[((long)b * NCTX + j0 + i) * CH + c0 + tx] / cnt;
  }
  __syncthreads();
  float* outp = (j0 < NT) ? (out1 + (long)b * CH * NT + j0)
                          : (out2 + (long)b * CH * NT + (j0 - NT));
#pragma unroll
  for (int i = ty; i < 32; i += 8)
    outp[(long)(c0 + i) * NT + tx] = tile[tx][i];
}

extern "C" void kernel_launch(void* const* d_in, const int* in_sizes, int n_in,
                              void* d_out, int out_size, void* d_ws, size_t ws_size,
                              hipStream_t stream) {
  const float* Xt  = (const float*)d_in[0];
  const float* Xc1 = (const float*)d_in[1];
  const float* Xc2 = (const float*)d_in[2];
  const float* W1  = (const float*)d_in[3];
  const float* b1  = (const float*)d_in[4];
  const float* W2  = (const float*)d_in[5];
  const float* b2  = (const float*)d_in[6];
  float* out = (float*)d_out;

  // ws layout (~69 MB):
  //   P: [BATCH*NCTX*CH]  XcT -> (after rescore+gemm1) contrib
  //   Q: [BATCH*NT*CH]    XtT -> X_edge
  //   R: [BATCH*NT*CH]    Xn_t -> X_et
  //   nrm, counts, cand, knn
  float* P = (float*)d_ws;
  float* Q = P + (long)BATCH * NCTX * CH;
  float* R = Q + (long)BATCH * NT * CH;
  float* nrm = R + (long)BATCH * NT * CH;
  unsigned* counts = (unsigned*)(nrm + (long)BATCH * NCTX);
  int* cand = (int*)(counts + (long)BATCH * NCTX);
  int* knn  = cand + (long)BATCH * NT * NSPLIT * CAND;

  // d_out doubles as scratch for Xn_c (32 MB) until the finalize kernels run
  float* Xn_c  = out;
  float* out_t  = out;
  float* out_c1 = out + (long)BATCH * CH * NT;
  float* out_c2 = out + 2L * BATCH * CH * NT;

  dim3 tb(32, 8);

  // node-major copies (for fp64 rescore and row-major GEMMs)
  k_transpose<<<dim3(NT / 32, CH / 32, BATCH), tb, 0, stream>>>(Xt,  Q, NT, (long)CH * NT, (long)NT * CH);
  k_transpose<<<dim3(NT / 32, CH / 32, BATCH), tb, 0, stream>>>(Xc1, P,                NT, (long)CH * NT, (long)NCTX * CH);
  k_transpose<<<dim3(NT / 32, CH / 32, BATCH), tb, 0, stream>>>(Xc2, P + (long)NT * CH, NT, (long)CH * NT, (long)NCTX * CH);

  k_norms<<<dim3(NCTX / 256, BATCH), 256, 0, stream>>>(Xc1, Xc2, nrm);

  // coarse fp32 scoring + top-16 per split
  k_dist_topk<<<dim3(NT / TMD, BATCH, NSPLIT), 256, 0, stream>>>(Xt, Xc1, Xc2, nrm, cand);

  // exact fp64 rescore -> knn[8]
  k_rescore<<<dim3(NT, BATCH), 64, 0, stream>>>(Q, P, cand, knn);

  hipMemsetAsync(counts, 0, (size_t)BATCH * NCTX * 4, stream);
  k_counts<<<dim3(BATCH * NT / 256), 256, 0, stream>>>(knn, counts);

  // node2edge linear: Xn_t -> R, Xn_c -> d_out scratch
  k_gemm_bias<<<dim3(NT / GTM, CH / GTN, BATCH), 256, 0, stream>>>(Q, W1, b1, R, NT);
  k_gemm_bias<<<dim3(NCTX / GTM, CH / GTN, BATCH), 256, 0, stream>>>(P, W1, b1, Xn_c, NCTX);

  // edge mean-pool -> Q (XtT dead)
  k_gather<<<dim3(NT, BATCH), 256, 0, stream>>>(R, Xn_c, knn, Q);

  // edge2node linear: X_et -> R (Xn_t dead)
  k_gemm_bias<<<dim3(NT / GTM, CH / GTN, BATCH), 256, 0, stream>>>(Q, W2, b2, R, NT);

  // out_t (overwrites dead Xn_c half of d_out)
  k_fin_t<<<dim3(NT / 32, CH / 32, BATCH), tb, 0, stream>>>(R, out_t);

  // context scatter-mean (P = XcT dead -> contrib)
  hipMemsetAsync(P, 0, (size_t)BATCH * NCTX * CH * 4, stream);
  k_scatter<<<dim3(NT, BATCH), 256, 0, stream>>>(R, knn, P);
  k_fin_c<<<dim3(NCTX / 32, CH / 32, BATCH), tb, 0, stream>>>(P, counts, out_c1, out_c2);
}

// Round 2
// 1470.367 us; speedup vs baseline: 2.5540x; 2.5540x over previous
//
#include <hip/hip_runtime.h>
#include <math.h>
#include <float.h>

#define BATCH 4
#define CH    256
#define NT    4096
#define NCTX  8192
#define KI    8

// coarse-selection geometry
#define CSEL    12                 // per-lane top-C
#define DNSPLIT 4                  // ctx splits
#define CTX_PER (NCTX / DNSPLIT)   // 2048
#define NTILE   (CTX_PER / 32)     // 64 tiles of 32 ctx
#define NCAND   (DNSPLIT * 2 * CSEL) // 96 candidates per target

typedef __attribute__((ext_vector_type(8)))  __bf16 bf16x8;
typedef __attribute__((ext_vector_type(16))) float  f32x16;

// ---------------- transpose: channel-major [CH][NT] -> node-major [NT][CH], fp32 + bf16 ----------------
__global__ __launch_bounds__(256) void k_transpose2(const float* __restrict__ src,
                                                    float* __restrict__ dstF,
                                                    unsigned short* __restrict__ dstB,
                                                    long dstBatch) {
  __shared__ float tile[32][33];
  const float* s = src + (long)blockIdx.z * CH * NT;
  float* dF = dstF + (long)blockIdx.z * dstBatch;
  unsigned short* dB = dstB + (long)blockIdx.z * dstBatch;
  const int m0 = blockIdx.x * 32, c0 = blockIdx.y * 32;
  const int tx = threadIdx.x, ty = threadIdx.y;
#pragma unroll
  for (int i = ty; i < 32; i += 8)
    tile[i][tx] = s[(long)(c0 + i) * NT + (m0 + tx)];
  __syncthreads();
#pragma unroll
  for (int i = ty; i < 32; i += 8) {
    float v = tile[tx][i];
    dF[(long)(m0 + i) * CH + (c0 + tx)] = v;
    unsigned u = __float_as_uint(v);
    dB[(long)(m0 + i) * CH + (c0 + tx)] =
        (unsigned short)((u + 0x7fffu + ((u >> 16) & 1u)) >> 16);  // RNE bf16
  }
}

// ---------------- context squared norms (fp32, coarse ranking only) ----------------
__global__ __launch_bounds__(256) void k_norms(const float* __restrict__ xc1,
                                               const float* __restrict__ xc2,
                                               float* __restrict__ nrm) {
  const int j = blockIdx.x * 256 + threadIdx.x;
  const int b = blockIdx.y;
  const float* src = (j < NT) ? (xc1 + (long)b * CH * NT + j)
                              : (xc2 + (long)b * CH * NT + (j - NT));
  float acc = 0.f;
#pragma unroll 8
  for (int c = 0; c < CH; ++c) {
    float v = src[(long)c * NT];
    acc = fmaf(v, v, acc);
  }
  nrm[(long)b * NCTX + j] = acc;
}

// ---------------- MFMA coarse scorer + per-lane top-CSEL ----------------
// Swapped GEMM: C[ctx(row)][tgt(col)] = Xc . Xt^T via mfma_f32_32x32x16_bf16.
// C/D layout: col = lane&31 (target), row = (reg&3) + 8*(reg>>2) + 4*(lane>>5) (ctx).
// A and B fragments both loaded with k = (lane>>5)*8 + e (same bijection for A and B,
// so any hardware k-ordering gives the exact same dot product).
__global__ __launch_bounds__(256) void k_dist_mfma(const __bf16* __restrict__ XcB,
                                                   const __bf16* __restrict__ XtB,
                                                   const float* __restrict__ nrm,
                                                   int* __restrict__ cand) {
  __shared__ __bf16 lds[2][32 * CH];   // 2 x 16 KB ctx tiles, fragment-linear order
  __shared__ float nrm_s[CTX_PER];     // 8 KB
  const int b = blockIdx.y, split = blockIdx.z;
  const int t = threadIdx.x, w = t >> 6, lane = t & 63;
  const int l31 = lane & 31, lh = lane >> 5;
  const int tgt0 = blockIdx.x * 128 + w * 32;
  const int cbase = split * CTX_PER;

  for (int i = t; i < CTX_PER; i += 256) nrm_s[i] = nrm[(long)b * NCTX + cbase + i];

  // B fragments (targets), K=256 in 16 k-steps, register-resident
  const __bf16* tp = XtB + ((long)b * NT + tgt0 + l31) * CH + lh * 8;
  bf16x8 bfrag[16];
#pragma unroll
  for (int s = 0; s < 16; ++s) bfrag[s] = *(const bf16x8*)(tp + s * 16);

  float bd[CSEL]; int bi[CSEL];
#pragma unroll
  for (int q = 0; q < CSEL; ++q) { bd[q] = FLT_MAX; bi[q] = 0x7fffffff; }

  const __bf16* cp = XcB + ((long)b * NCTX + cbase + l31) * CH;

  // stage tile jt into lds[buf]: chunk c=(r*4+w)*64+lane holds ctx=lane&31, k8=(r*4+w)*2+(lane>>5)
  // -> LDS linear at (r*4+w)*1024B + lane*16B; ds_read for k-step s is then fully conflict-free.
  auto STAGE = [&](int buf, int jt) {
#pragma unroll
    for (int r = 0; r < 4; ++r) {
      const __bf16* src = cp + (long)jt * 32 * CH + ((r * 4 + w) * 2 + lh) * 8;
      __bf16* dst = &lds[buf][(r * 4 + w) * 512];   // wave-uniform base; HW adds lane*16
      __builtin_amdgcn_global_load_lds((const __attribute__((address_space(1))) void*)src,
                                       (__attribute__((address_space(3))) void*)dst,
                                       16, 0, 0);
    }
  };

  STAGE(0, 0);
  __syncthreads();

  int cur = 0;
  for (int jt = 0; jt < NTILE; ++jt) {
    if (jt + 1 < NTILE) STAGE(cur ^ 1, jt + 1);

    f32x16 acc;
#pragma unroll
    for (int i = 0; i < 16; ++i) acc[i] = 0.f;
#pragma unroll
    for (int s = 0; s < 16; ++s) {
      bf16x8 a = *(const bf16x8*)(&lds[cur][s * 512 + lane * 8]);
      acc = __builtin_amdgcn_mfma_f32_32x32x16_bf16(a, bfrag[s], acc, 0, 0, 0);
    }

    const int ct0 = jt * 32;
#pragma unroll
    for (int reg = 0; reg < 16; ++reg) {
      const int row = (reg & 3) + 8 * (reg >> 2) + lh * 4;
      float sc = nrm_s[ct0 + row] - 2.0f * acc[reg];
      if (sc < bd[CSEL - 1]) {
        int j = cbase + ct0 + row;
#pragma unroll
        for (int q = 0; q < CSEL; ++q) {
          bool lt = sc < bd[q];
          float od = bd[q]; int oi = bi[q];
          if (lt) { bd[q] = sc; bi[q] = j; sc = od; j = oi; }
        }
      }
    }
    __syncthreads();   // drains vmcnt (stage writes) + lgkm; frees read buffer
    cur ^= 1;
  }

  long ob = (((long)b * NT + tgt0 + l31) * DNSPLIT + split) * (2 * CSEL) + lh * CSEL;
#pragma unroll
  for (int q = 0; q < CSEL; ++q) cand[ob + q] = bi[q];
}

// ---------------- fp64 exact rescore of NCAND candidates -> knn[8] ----------------
__global__ __launch_bounds__(64) void k_rescore(const float* __restrict__ XtT,
                                                const float* __restrict__ XcT,
                                                const int* __restrict__ cand,
                                                int* __restrict__ knn) {
  const int n = blockIdx.x, b = blockIdx.y, lane = threadIdx.x;
  __shared__ double sd[NCAND];
  __shared__ int    sj[NCAND];
  const float* xt = XtT + ((long)b * NT + n) * CH;
  float4 xa = *(const float4*)(xt + lane * 4);
  const int* cd = cand + ((long)b * NT + n) * NCAND;
  for (int q = 0; q < NCAND; ++q) {
    int j = cd[q];
    const float* xc = XcT + ((long)b * NCTX + j) * CH;
    float4 xb = *(const float4*)(xc + lane * 4);
    double d0 = (double)xa.x - (double)xb.x;
    double acc = d0 * d0;
    double d1 = (double)xa.y - (double)xb.y; acc += d1 * d1;
    double d2 = (double)xa.z - (double)xb.z; acc += d2 * d2;
    double d3 = (double)xa.w - (double)xb.w; acc += d3 * d3;
#pragma unroll
    for (int off = 32; off > 0; off >>= 1) acc += __shfl_down(acc, off);
    if (lane == 0) { sd[q] = acc; sj[q] = j; }
  }
  __syncthreads();
  if (lane == 0) {
    long obase = ((long)b * NT + n) * KI;
    for (int r = 0; r < KI; ++r) {
      double best = DBL_MAX; int bj = 0x7fffffff; int bq = 0;
      for (int q = 0; q < NCAND; ++q) {
        double d = sd[q]; int j = sj[q];
        if (d < best || (d == best && j < bj)) { best = d; bj = j; bq = q; }
      }
      sd[bq] = DBL_MAX;
      knn[obase + r] = bj;
    }
  }
}

// ---------------- counts (segment_sum of ones) ----------------
__global__ __launch_bounds__(256) void k_counts(const int* __restrict__ knn,
                                                unsigned* __restrict__ counts) {
  const int idx = blockIdx.x * 256 + threadIdx.x;   // over BATCH*NT
  const int b = idx >> 12;                          // NT = 4096
  const int* kn = knn + (long)idx * KI;
#pragma unroll
  for (int q = 0; q < KI; ++q) atomicAdd(&counts[(long)b * NCTX + kn[q]], 1u);
}

// ---------------- GEMM + bias: out[M][CH] = A[M][CH] @ W[CH][CH] + b ----------------
#define GTM 64
#define GTN 64
#define GKC 32
__global__ __launch_bounds__(256) void k_gemm_bias(const float* __restrict__ A,
                                                   const float* __restrict__ Wm,
                                                   const float* __restrict__ bias,
                                                   float* __restrict__ out, int M) {
  __shared__ float As[GKC][GTM + 4];
  __shared__ float Bs[GKC][GTN];
  const int b = blockIdx.z;
  const long m0 = (long)blockIdx.x * GTM;
  const int n0 = blockIdx.y * GTN;
  const float* Ab = A + (long)b * M * CH;
  float* ob = out + (long)b * M * CH;
  const int t = threadIdx.x;
  const int tm = (t & 15) * 4;
  const int tn = (t >> 4) * 4;
  float acc[4][4] = {{0.f}};
  for (int kc = 0; kc < CH; kc += GKC) {
    __syncthreads();
#pragma unroll
    for (int rep = 0; rep < 2; ++rep) {
      int p = t + rep * 256;
      int row = p >> 3;
      int ck = (p & 7) * 4;
      float4 va = *(const float4*)(Ab + (m0 + row) * CH + kc + ck);
      As[ck + 0][row] = va.x;
      As[ck + 1][row] = va.y;
      As[ck + 2][row] = va.z;
      As[ck + 3][row] = va.w;
      int rowb = p >> 4;
      int cn = (p & 15) * 4;
      *(float4*)&Bs[rowb][cn] = *(const float4*)(Wm + (long)(kc + rowb) * CH + n0 + cn);
    }
    __syncthreads();
#pragma unroll 8
    for (int k = 0; k < GKC; ++k) {
      float av[4], bv[4];
      *(float4*)av = *(const float4*)&As[k][tm];
      *(float4*)bv = *(const float4*)&Bs[k][tn];
#pragma unroll
      for (int r = 0; r < 4; ++r)
#pragma unroll
        for (int c2 = 0; c2 < 4; ++c2)
          acc[r][c2] = fmaf(av[r], bv[c2], acc[r][c2]);
    }
  }
#pragma unroll
  for (int r = 0; r < 4; ++r) {
    float4 ov;
    ov.x = acc[r][0] + bias[n0 + tn + 0];
    ov.y = acc[r][1] + bias[n0 + tn + 1];
    ov.z = acc[r][2] + bias[n0 + tn + 2];
    ov.w = acc[r][3] + bias[n0 + tn + 3];
    *(float4*)(ob + (m0 + tm + r) * CH + n0 + tn) = ov;
  }
}

// ---------------- gather-mean: X_edge = (Xn_t + sum_k Xn_c[knn]) / 9 ----------------
__global__ __launch_bounds__(256) void k_gather(const float* __restrict__ Xn_t,
                                                const float* __restrict__ Xn_c,
                                                const int* __restrict__ knn,
                                                float* __restrict__ Xe) {
  const int n = blockIdx.x, b = blockIdx.y, c = threadIdx.x;
  const int* kn = knn + ((long)b * NT + n) * KI;
  int j[KI];
#pragma unroll
  for (int q = 0; q < KI; ++q) j[q] = kn[q];
  float acc = Xn_t[((long)b * NT + n) * CH + c];
#pragma unroll
  for (int q = 0; q < KI; ++q) acc += Xn_c[((long)b * NCTX + j[q]) * CH + c];
  Xe[((long)b * NT + n) * CH + c] = acc / 9.0f;
}

// ---------------- scatter-add contributions to context nodes ----------------
__global__ __launch_bounds__(256) void k_scatter(const float* __restrict__ Xet,
                                                 const int* __restrict__ knn,
                                                 float* __restrict__ contrib) {
  const int n = blockIdx.x, b = blockIdx.y, c = threadIdx.x;
  const float v = Xet[((long)b * NT + n) * CH + c];
  const int* kn = knn + ((long)b * NT + n) * KI;
#pragma unroll
  for (int q = 0; q < KI; ++q)
    atomicAdd(&contrib[((long)b * NCTX + kn[q]) * CH + c], v);
}

// ---------------- finalize target output: transpose [NT][CH] -> image [CH][NT] ----------------
__global__ __launch_bounds__(256) void k_fin_t(const float* __restrict__ Xet,
                                               float* __restrict__ out) {
  __shared__ float tile[32][33];
  const int b = blockIdx.z;
  const int n0 = blockIdx.x * 32, c0 = blockIdx.y * 32;
  const int tx = threadIdx.x, ty = threadIdx.y;
#pragma unroll
  for (int i = ty; i < 32; i += 8)
    tile[i][tx] = Xet[((long)b * NT + n0 + i) * CH + c0 + tx];
  __syncthreads();
#pragma unroll
  for (int i = ty; i < 32; i += 8)
    out[((long)b * CH + c0 + i) * NT + n0 + tx] = tile[tx][i];
}

// ---------------- finalize context outputs: divide by counts, transpose, split ----------------
__global__ __launch_bounds__(256) void k_fin_c(const float* __restrict__ contrib,
                                               const unsigned* __restrict__ counts,
                                               float* __restrict__ out1,
                                               float* __restrict__ out2) {
  __shared__ float tile[32][33];
  const int b = blockIdx.z;
  const int j0 = blockIdx.x * 32, c0 = blockIdx.y * 32;
  const int tx = threadIdx.x, ty = threadIdx.y;
#pragma unroll
  for (int i = ty; i < 32; i += 8) {
    float cnt = fmaxf((float)counts[(long)b * NCTX + j0 + i], 1.0f);
    tile[i][tx] = contrib[((long)b * NCTX + j0 + i) * CH + c0 + tx] / cnt;
  }
  __syncthreads();
  float* outp = (j0 < NT) ? (out1 + (long)b * CH * NT + j0)
                          : (out2 + (long)b * CH * NT + (j0 - NT));
#pragma unroll
  for (int i = ty; i < 32; i += 8)
    outp[(long)(c0 + i) * NT + tx] = tile[tx][i];
}

extern "C" void kernel_launch(void* const* d_in, const int* in_sizes, int n_in,
                              void* d_out, int out_size, void* d_ws, size_t ws_size,
                              hipStream_t stream) {
  const float* Xt  = (const float*)d_in[0];
  const float* Xc1 = (const float*)d_in[1];
  const float* Xc2 = (const float*)d_in[2];
  const float* W1  = (const float*)d_in[3];
  const float* b1  = (const float*)d_in[4];
  const float* W2  = (const float*)d_in[5];
  const float* b2  = (const float*)d_in[6];
  float* out = (float*)d_out;

  // ws layout (~65 MB):
  //   P: [BATCH*NCTX*CH]  XcT fp32 -> (after gemm1) contrib
  //   Q: [BATCH*NT*CH]    XtT fp32 -> X_edge
  //   R: [BATCH*NT*CH]    Xn_t -> X_et
  //   nrm, counts, knn
  float* P = (float*)d_ws;
  float* Q = P + (long)BATCH * NCTX * CH;
  float* R = Q + (long)BATCH * NT * CH;
  float* nrm = R + (long)BATCH * NT * CH;
  unsigned* counts = (unsigned*)(nrm + (long)BATCH * NCTX);
  int* knn = (int*)(counts + (long)BATCH * NCTX);

  // d_out (50.3 MB) doubles as scratch until gemm1/finalize overwrite it:
  //   [XcB bf16 16.8MB | XtB bf16 8.4MB | cand 6.3MB]  -- all dead after k_rescore
  unsigned short* XcB = (unsigned short*)d_out;
  unsigned short* XtB = XcB + (long)BATCH * NCTX * CH;
  int* cand = (int*)(XtB + (long)BATCH * NT * CH);

  float* Xn_c  = out;   // written after rescore (scratch region dead by then)
  float* out_t  = out;
  float* out_c1 = out + (long)BATCH * CH * NT;
  float* out_c2 = out + 2L * BATCH * CH * NT;

  dim3 tb(32, 8);

  // node-major fp32 (rescore) + bf16 (MFMA) copies
  k_transpose2<<<dim3(NT / 32, CH / 32, BATCH), tb, 0, stream>>>(Xt,  Q, XtB, (long)NT * CH);
  k_transpose2<<<dim3(NT / 32, CH / 32, BATCH), tb, 0, stream>>>(Xc1, P, XcB, (long)NCTX * CH);
  k_transpose2<<<dim3(NT / 32, CH / 32, BATCH), tb, 0, stream>>>(Xc2, P + (long)NT * CH,
                                                                 XcB + (long)NT * CH,
                                                                 (long)NCTX * CH);

  k_norms<<<dim3(NCTX / 256, BATCH), 256, 0, stream>>>(Xc1, Xc2, nrm);

  // MFMA coarse scoring + per-lane top-12 -> 96 candidates per target
  k_dist_mfma<<<dim3(NT / 128, BATCH, DNSPLIT), 256, 0, stream>>>(
      (const __bf16*)XcB, (const __bf16*)XtB, nrm, cand);

  // exact fp64 rescore -> knn[8]
  k_rescore<<<dim3(NT, BATCH), 64, 0, stream>>>(Q, P, cand, knn);

  hipMemsetAsync(counts, 0, (size_t)BATCH * NCTX * 4, stream);
  k_counts<<<dim3(BATCH * NT / 256), 256, 0, stream>>>(knn, counts);

  // node2edge linear: Xn_t -> R, Xn_c -> d_out scratch (XcB/XtB/cand dead now)
  k_gemm_bias<<<dim3(NT / GTM, CH / GTN, BATCH), 256, 0, stream>>>(Q, W1, b1, R, NT);
  k_gemm_bias<<<dim3(NCTX / GTM, CH / GTN, BATCH), 256, 0, stream>>>(P, W1, b1, Xn_c, NCTX);

  // edge mean-pool -> Q (XtT dead)
  k_gather<<<dim3(NT, BATCH), 256, 0, stream>>>(R, Xn_c, knn, Q);

  // edge2node linear: X_et -> R (Xn_t dead)
  k_gemm_bias<<<dim3(NT / GTM, CH / GTN, BATCH), 256, 0, stream>>>(Q, W2, b2, R, NT);

  // out_t (overwrites dead Xn_c region of d_out)
  k_fin_t<<<dim3(NT / 32, CH / 32, BATCH), tb, 0, stream>>>(R, out_t);

  // context scatter-mean (P = XcT dead -> contrib)
  hipMemsetAsync(P, 0, (size_t)BATCH * NCTX * CH * 4, stream);
  k_scatter<<<dim3(NT, BATCH), 256, 0, stream>>>(R, knn, P);
  k_fin_c<<<dim3(NCTX / 32, CH / 32, BATCH), tb, 0, stream>>>(P, counts, out_c1, out_c2);
}

// Round 3
// 777.550 us; speedup vs baseline: 4.8296x; 1.8910x over previous
//
#include <hip/hip_runtime.h>
#include <math.h>
#include <float.h>

#define BATCH 4
#define CH    256
#define NT    4096
#define NCTX  8192
#define KI    8

// coarse-selection geometry
#define CSEL    10                 // per-lane top-C (>=8 => cannot miss true top-8)
#define DNSPLIT 4                  // ctx splits
#define CTX_PER (NCTX / DNSPLIT)   // 2048
#define NTILE   (CTX_PER / 32)     // 64 tiles of 32 ctx
#define NCAND   (DNSPLIT * 2 * CSEL) // 80 candidates per target

typedef __attribute__((ext_vector_type(8)))  __bf16 bf16x8;
typedef __attribute__((ext_vector_type(16))) float  f32x16;

// ---------------- transpose: channel-major [CH][NT] -> node-major [NT][CH], fp32 + bf16 ----------------
__global__ __launch_bounds__(256) void k_transpose2(const float* __restrict__ src,
                                                    float* __restrict__ dstF,
                                                    unsigned short* __restrict__ dstB,
                                                    long dstBatch) {
  __shared__ float tile[32][33];
  const float* s = src + (long)blockIdx.z * CH * NT;
  float* dF = dstF + (long)blockIdx.z * dstBatch;
  unsigned short* dB = dstB + (long)blockIdx.z * dstBatch;
  const int m0 = blockIdx.x * 32, c0 = blockIdx.y * 32;
  const int tx = threadIdx.x, ty = threadIdx.y;
#pragma unroll
  for (int i = ty; i < 32; i += 8)
    tile[i][tx] = s[(long)(c0 + i) * NT + (m0 + tx)];
  __syncthreads();
#pragma unroll
  for (int i = ty; i < 32; i += 8) {
    float v = tile[tx][i];
    dF[(long)(m0 + i) * CH + (c0 + tx)] = v;
    unsigned u = __float_as_uint(v);
    dB[(long)(m0 + i) * CH + (c0 + tx)] =
        (unsigned short)((u + 0x7fffu + ((u >> 16) & 1u)) >> 16);  // RNE bf16
  }
}

// ---------------- context squared norms (fp32, coarse ranking only) ----------------
__global__ __launch_bounds__(256) void k_norms(const float* __restrict__ xc1,
                                               const float* __restrict__ xc2,
                                               float* __restrict__ nrm) {
  const int j = blockIdx.x * 256 + threadIdx.x;
  const int b = blockIdx.y;
  const float* src = (j < NT) ? (xc1 + (long)b * CH * NT + j)
                              : (xc2 + (long)b * CH * NT + (j - NT));
  float acc = 0.f;
#pragma unroll 8
  for (int c = 0; c < CH; ++c) {
    float v = src[(long)c * NT];
    acc = fmaf(v, v, acc);
  }
  nrm[(long)b * NCTX + j] = acc;
}

// ---------------- MFMA coarse scorer + per-lane top-CSEL (packed-key min/max bubble) ----------------
// Swapped GEMM: C[ctx(row)][tgt(col)] = Xc . Xt^T via mfma_f32_32x32x16_bf16.
// C/D layout: col = lane&31 (target), row = (reg&3) + 8*(reg>>2) + 4*(lane>>5) (ctx).
// acc initialized with -0.5*nrm_c so score = -2*acc + 512 = d^2 - nrm_t + 512 > 0.
// key = (float_bits(score) & ~0x7FF) | local_ctx_idx  (11-bit idx in low mantissa;
// <=0.25 score noise, absorbed by fp64 rescore). Branchless 10-deep min/max bubble.
__global__ __launch_bounds__(256) void k_dist_mfma(const __bf16* __restrict__ XcB,
                                                   const __bf16* __restrict__ XtB,
                                                   const float* __restrict__ nrm,
                                                   int* __restrict__ cand) {
  __shared__ __bf16 lds[2][32 * CH];   // 2 x 16 KB ctx tiles, fragment-linear order
  __shared__ float nrm_s[CTX_PER];     // 8 KB, holds -0.5*nrm
  const int b = blockIdx.y, split = blockIdx.z;
  const int t = threadIdx.x, w = t >> 6, lane = t & 63;
  const int l31 = lane & 31, lh = lane >> 5;
  const int tgt0 = blockIdx.x * 128 + w * 32;
  const int cbase = split * CTX_PER;

  for (int i = t; i < CTX_PER; i += 256)
    nrm_s[i] = -0.5f * nrm[(long)b * NCTX + cbase + i];

  // B fragments (targets), K=256 in 16 k-steps, register-resident
  const __bf16* tp = XtB + ((long)b * NT + tgt0 + l31) * CH + lh * 8;
  bf16x8 bfrag[16];
#pragma unroll
  for (int s = 0; s < 16; ++s) bfrag[s] = *(const bf16x8*)(tp + s * 16);

  unsigned kd[CSEL];
#pragma unroll
  for (int q = 0; q < CSEL; ++q) kd[q] = 0xFFFFFFFFu;

  const __bf16* cp = XcB + ((long)b * NCTX + cbase + l31) * CH;

  // stage tile jt into lds[buf]: chunk c=(r*4+w)*64+lane holds ctx=lane&31, k8=(r*4+w)*2+(lane>>5)
  // -> LDS linear at (r*4+w)*1024B + lane*16B; ds_read for k-step s is then fully conflict-free.
  auto STAGE = [&](int buf, int jt) {
#pragma unroll
    for (int r = 0; r < 4; ++r) {
      const __bf16* src = cp + (long)jt * 32 * CH + ((r * 4 + w) * 2 + lh) * 8;
      __bf16* dst = &lds[buf][(r * 4 + w) * 512];   // wave-uniform base; HW adds lane*16
      __builtin_amdgcn_global_load_lds((const __attribute__((address_space(1))) void*)src,
                                       (__attribute__((address_space(3))) void*)dst,
                                       16, 0, 0);
    }
  };

  STAGE(0, 0);
  __syncthreads();

  int cur = 0;
  for (int jt = 0; jt < NTILE; ++jt) {
    if (jt + 1 < NTILE) STAGE(cur ^ 1, jt + 1);

    const int ct0 = jt * 32;
    f32x16 acc;
#pragma unroll
    for (int g = 0; g < 4; ++g) {      // acc[4g+j] = -0.5*nrm[ct0 + 8g + 4lh + j]
      float4 nv = *(const float4*)&nrm_s[ct0 + 8 * g + 4 * lh];
      acc[4 * g + 0] = nv.x; acc[4 * g + 1] = nv.y;
      acc[4 * g + 2] = nv.z; acc[4 * g + 3] = nv.w;
    }
#pragma unroll
    for (int s = 0; s < 16; ++s) {
      bf16x8 a = *(const bf16x8*)(&lds[cur][s * 512 + lane * 8]);
      acc = __builtin_amdgcn_mfma_f32_32x32x16_bf16(a, bfrag[s], acc, 0, 0, 0);
    }

#pragma unroll
    for (int reg = 0; reg < 16; ++reg) {
      const int row = (reg & 3) + 8 * (reg >> 2) + lh * 4;
      float sc = fmaf(acc[reg], -2.0f, 512.0f);
      unsigned key = (__float_as_uint(sc) & 0xFFFFF800u) | (unsigned)ct0 | (unsigned)row;
#pragma unroll
      for (int q = 0; q < CSEL; ++q) {   // branchless sorted-ascending bubble insert
        unsigned lo = min(key, kd[q]);
        key = max(key, kd[q]);
        kd[q] = lo;
      }
    }
    __syncthreads();   // drains vmcnt (stage writes) + lgkm; frees read buffer
    cur ^= 1;
  }

  long ob = (((long)b * NT + tgt0 + l31) * DNSPLIT + split) * (2 * CSEL) + lh * CSEL;
#pragma unroll
  for (int q = 0; q < CSEL; ++q) cand[ob + q] = cbase + (int)(kd[q] & 0x7FFu);
}

// ---------------- fp64 exact rescore of NCAND candidates -> knn[8] ----------------
__global__ __launch_bounds__(64) void k_rescore(const float* __restrict__ XtT,
                                                const float* __restrict__ XcT,
                                                const int* __restrict__ cand,
                                                int* __restrict__ knn) {
  const int n = blockIdx.x, b = blockIdx.y, lane = threadIdx.x;
  __shared__ double sd[NCAND];
  __shared__ int    sj[NCAND];
  const float* xt = XtT + ((long)b * NT + n) * CH;
  float4 xa = *(const float4*)(xt + lane * 4);
  const int* cd = cand + ((long)b * NT + n) * NCAND;
  for (int q = 0; q < NCAND; ++q) {
    int j = cd[q];
    const float* xc = XcT + ((long)b * NCTX + j) * CH;
    float4 xb = *(const float4*)(xc + lane * 4);
    double d0 = (double)xa.x - (double)xb.x;
    double acc = d0 * d0;
    double d1 = (double)xa.y - (double)xb.y; acc += d1 * d1;
    double d2 = (double)xa.z - (double)xb.z; acc += d2 * d2;
    double d3 = (double)xa.w - (double)xb.w; acc += d3 * d3;
#pragma unroll
    for (int off = 32; off > 0; off >>= 1) acc += __shfl_down(acc, off);
    if (lane == 0) { sd[q] = acc; sj[q] = j; }
  }
  __syncthreads();
  if (lane == 0) {
    long obase = ((long)b * NT + n) * KI;
    for (int r = 0; r < KI; ++r) {
      double best = DBL_MAX; int bj = 0x7fffffff; int bq = 0;
      for (int q = 0; q < NCAND; ++q) {
        double d = sd[q]; int j = sj[q];
        if (d < best || (d == best && j < bj)) { best = d; bj = j; bq = q; }
      }
      sd[bq] = DBL_MAX;
      knn[obase + r] = bj;
    }
  }
}

// ---------------- counts (segment_sum of ones) ----------------
__global__ __launch_bounds__(256) void k_counts(const int* __restrict__ knn,
                                                unsigned* __restrict__ counts) {
  const int idx = blockIdx.x * 256 + threadIdx.x;   // over BATCH*NT
  const int b = idx >> 12;                          // NT = 4096
  const int* kn = knn + (long)idx * KI;
#pragma unroll
  for (int q = 0; q < KI; ++q) atomicAdd(&counts[(long)b * NCTX + kn[q]], 1u);
}

// ---------------- GEMM + bias: out[M][CH] = A[M][CH] @ W[CH][CH] + b ----------------
#define GTM 64
#define GTN 64
#define GKC 32
__global__ __launch_bounds__(256) void k_gemm_bias(const float* __restrict__ A,
                                                   const float* __restrict__ Wm,
                                                   const float* __restrict__ bias,
                                                   float* __restrict__ out, int M) {
  __shared__ float As[GKC][GTM + 4];
  __shared__ float Bs[GKC][GTN];
  const int b = blockIdx.z;
  const long m0 = (long)blockIdx.x * GTM;
  const int n0 = blockIdx.y * GTN;
  const float* Ab = A + (long)b * M * CH;
  float* ob = out + (long)b * M * CH;
  const int t = threadIdx.x;
  const int tm = (t & 15) * 4;
  const int tn = (t >> 4) * 4;
  float acc[4][4] = {{0.f}};
  for (int kc = 0; kc < CH; kc += GKC) {
    __syncthreads();
#pragma unroll
    for (int rep = 0; rep < 2; ++rep) {
      int p = t + rep * 256;
      int row = p >> 3;
      int ck = (p & 7) * 4;
      float4 va = *(const float4*)(Ab + (m0 + row) * CH + kc + ck);
      As[ck + 0][row] = va.x;
      As[ck + 1][row] = va.y;
      As[ck + 2][row] = va.z;
      As[ck + 3][row] = va.w;
      int rowb = p >> 4;
      int cn = (p & 15) * 4;
      *(float4*)&Bs[rowb][cn] = *(const float4*)(Wm + (long)(kc + rowb) * CH + n0 + cn);
    }
    __syncthreads();
#pragma unroll 8
    for (int k = 0; k < GKC; ++k) {
      float av[4], bv[4];
      *(float4*)av = *(const float4*)&As[k][tm];
      *(float4*)bv = *(const float4*)&Bs[k][tn];
#pragma unroll
      for (int r = 0; r < 4; ++r)
#pragma unroll
        for (int c2 = 0; c2 < 4; ++c2)
          acc[r][c2] = fmaf(av[r], bv[c2], acc[r][c2]);
    }
  }
#pragma unroll
  for (int r = 0; r < 4; ++r) {
    float4 ov;
    ov.x = acc[r][0] + bias[n0 + tn + 0];
    ov.y = acc[r][1] + bias[n0 + tn + 1];
    ov.z = acc[r][2] + bias[n0 + tn + 2];
    ov.w = acc[r][3] + bias[n0 + tn + 3];
    *(float4*)(ob + (m0 + tm + r) * CH + n0 + tn) = ov;
  }
}

// ---------------- gather-mean: X_edge = (Xn_t + sum_k Xn_c[knn]) / 9 ----------------
__global__ __launch_bounds__(256) void k_gather(const float* __restrict__ Xn_t,
                                                const float* __restrict__ Xn_c,
                                                const int* __restrict__ knn,
                                                float* __restrict__ Xe) {
  const int n = blockIdx.x, b = blockIdx.y, c = threadIdx.x;
  const int* kn = knn + ((long)b * NT + n) * KI;
  int j[KI];
#pragma unroll
  for (int q = 0; q < KI; ++q) j[q] = kn[q];
  float acc = Xn_t[((long)b * NT + n) * CH + c];
#pragma unroll
  for (int q = 0; q < KI; ++q) acc += Xn_c[((long)b * NCTX + j[q]) * CH + c];
  Xe[((long)b * NT + n) * CH + c] = acc / 9.0f;
}

// ---------------- scatter-add contributions to context nodes ----------------
__global__ __launch_bounds__(256) void k_scatter(const float* __restrict__ Xet,
                                                 const int* __restrict__ knn,
                                                 float* __restrict__ contrib) {
  const int n = blockIdx.x, b = blockIdx.y, c = threadIdx.x;
  const float v = Xet[((long)b * NT + n) * CH + c];
  const int* kn = knn + ((long)b * NT + n) * KI;
#pragma unroll
  for (int q = 0; q < KI; ++q)
    atomicAdd(&contrib[((long)b * NCTX + kn[q]) * CH + c], v);
}

// ---------------- finalize target output: transpose [NT][CH] -> image [CH][NT] ----------------
__global__ __launch_bounds__(256) void k_fin_t(const float* __restrict__ Xet,
                                               float* __restrict__ out) {
  __shared__ float tile[32][33];
  const int b = blockIdx.z;
  const int n0 = blockIdx.x * 32, c0 = blockIdx.y * 32;
  const int tx = threadIdx.x, ty = threadIdx.y;
#pragma unroll
  for (int i = ty; i < 32; i += 8)
    tile[i][tx] = Xet[((long)b * NT + n0 + i) * CH + c0 + tx];
  __syncthreads();
#pragma unroll
  for (int i = ty; i < 32; i += 8)
    out[((long)b * CH + c0 + i) * NT + n0 + tx] = tile[tx][i];
}

// ---------------- finalize context outputs: divide by counts, transpose, split ----------------
__global__ __launch_bounds__(256) void k_fin_c(const float* __restrict__ contrib,
                                               const unsigned* __restrict__ counts,
                                               float* __restrict__ out1,
                                               float* __restrict__ out2) {
  __shared__ float tile[32][33];
  const int b = blockIdx.z;
  const int j0 = blockIdx.x * 32, c0 = blockIdx.y * 32;
  const int tx = threadIdx.x, ty = threadIdx.y;
#pragma unroll
  for (int i = ty; i < 32; i += 8) {
    float cnt = fmaxf((float)counts[(long)b * NCTX + j0 + i], 1.0f);
    tile[i][tx] = contrib[((long)b * NCTX + j0 + i) * CH + c0 + tx] / cnt;
  }
  __syncthreads();
  float* outp = (j0 < NT) ? (out1 + (long)b * CH * NT + j0)
                          : (out2 + (long)b * CH * NT + (j0 - NT));
#pragma unroll
  for (int i = ty; i < 32; i += 8)
    outp[(long)(c0 + i) * NT + tx] = tile[tx][i];
}

extern "C" void kernel_launch(void* const* d_in, const int* in_sizes, int n_in,
                              void* d_out, int out_size, void* d_ws, size_t ws_size,
                              hipStream_t stream) {
  const float* Xt  = (const float*)d_in[0];
  const float* Xc1 = (const float*)d_in[1];
  const float* Xc2 = (const float*)d_in[2];
  const float* W1  = (const float*)d_in[3];
  const float* b1  = (const float*)d_in[4];
  const float* W2  = (const float*)d_in[5];
  const float* b2  = (const float*)d_in[6];
  float* out = (float*)d_out;

  // ws layout (~65 MB):
  //   P: [BATCH*NCTX*CH]  XcT fp32 -> (after gemm1) contrib
  //   Q: [BATCH*NT*CH]    XtT fp32 -> X_edge
  //   R: [BATCH*NT*CH]    Xn_t -> X_et
  //   nrm, counts, knn
  float* P = (float*)d_ws;
  float* Q = P + (long)BATCH * NCTX * CH;
  float* R = Q + (long)BATCH * NT * CH;
  float* nrm = R + (long)BATCH * NT * CH;
  unsigned* counts = (unsigned*)(nrm + (long)BATCH * NCTX);
  int* knn = (int*)(counts + (long)BATCH * NCTX);

  // d_out (50.3 MB) doubles as scratch until gemm1/finalize overwrite it:
  //   [XcB bf16 16.8MB | XtB bf16 8.4MB | cand 5.2MB]  -- all dead after k_rescore
  unsigned short* XcB = (unsigned short*)d_out;
  unsigned short* XtB = XcB + (long)BATCH * NCTX * CH;
  int* cand = (int*)(XtB + (long)BATCH * NT * CH);

  float* Xn_c  = out;   // written after rescore (scratch region dead by then)
  float* out_t  = out;
  float* out_c1 = out + (long)BATCH * CH * NT;
  float* out_c2 = out + 2L * BATCH * CH * NT;

  dim3 tb(32, 8);

  // node-major fp32 (rescore) + bf16 (MFMA) copies
  k_transpose2<<<dim3(NT / 32, CH / 32, BATCH), tb, 0, stream>>>(Xt,  Q, XtB, (long)NT * CH);
  k_transpose2<<<dim3(NT / 32, CH / 32, BATCH), tb, 0, stream>>>(Xc1, P, XcB, (long)NCTX * CH);
  k_transpose2<<<dim3(NT / 32, CH / 32, BATCH), tb, 0, stream>>>(Xc2, P + (long)NT * CH,
                                                                 XcB + (long)NT * CH,
                                                                 (long)NCTX * CH);

  k_norms<<<dim3(NCTX / 256, BATCH), 256, 0, stream>>>(Xc1, Xc2, nrm);

  // MFMA coarse scoring + per-lane top-10 -> 80 candidates per target
  k_dist_mfma<<<dim3(NT / 128, BATCH, DNSPLIT), 256, 0, stream>>>(
      (const __bf16*)XcB, (const __bf16*)XtB, nrm, cand);

  // exact fp64 rescore -> knn[8]
  k_rescore<<<dim3(NT, BATCH), 64, 0, stream>>>(Q, P, cand, knn);

  hipMemsetAsync(counts, 0, (size_t)BATCH * NCTX * 4, stream);
  k_counts<<<dim3(BATCH * NT / 256), 256, 0, stream>>>(knn, counts);

  // node2edge linear: Xn_t -> R, Xn_c -> d_out scratch (XcB/XtB/cand dead now)
  k_gemm_bias<<<dim3(NT / GTM, CH / GTN, BATCH), 256, 0, stream>>>(Q, W1, b1, R, NT);
  k_gemm_bias<<<dim3(NCTX / GTM, CH / GTN, BATCH), 256, 0, stream>>>(P, W1, b1, Xn_c, NCTX);

  // edge mean-pool -> Q (XtT dead)
  k_gather<<<dim3(NT, BATCH), 256, 0, stream>>>(R, Xn_c, knn, Q);

  // edge2node linear: X_et -> R (Xn_t dead)
  k_gemm_bias<<<dim3(NT / GTM, CH / GTN, BATCH), 256, 0, stream>>>(Q, W2, b2, R, NT);

  // out_t (overwrites dead Xn_c region of d_out)
  k_fin_t<<<dim3(NT / 32, CH / 32, BATCH), tb, 0, stream>>>(R, out_t);

  // context scatter-mean (P = XcT dead -> contrib)
  hipMemsetAsync(P, 0, (size_t)BATCH * NCTX * CH * 4, stream);
  k_scatter<<<dim3(NT, BATCH), 256, 0, stream>>>(R, knn, P);
  k_fin_c<<<dim3(NCTX / 32, CH / 32, BATCH), tb, 0, stream>>>(P, counts, out_c1, out_c2);
}

// Round 4
// 521.348 us; speedup vs baseline: 7.2030x; 1.4914x over previous
//
#include <hip/hip_runtime.h>
#include <math.h>
#include <float.h>

#define BATCH 4
#define CH    256
#define NT    4096
#define NCTX  8192
#define KI    8

// coarse-selection geometry
#define CSEL    10                 // per-split top-C after lane-half merge (>=8 => safe)
#define DNSPLIT 4                  // ctx splits
#define CTX_PER (NCTX / DNSPLIT)   // 2048
#define NTILE   (CTX_PER / 32)     // 64 tiles of 32 ctx
#define NCAND   (DNSPLIT * CSEL)   // 40 candidates per target

typedef __attribute__((ext_vector_type(8)))  __bf16 bf16x8;
typedef __attribute__((ext_vector_type(16))) float  f32x16;

// ---------------- transpose: channel-major [CH][NT] -> node-major [NT][CH], fp32 + bf16 ----------------
__global__ __launch_bounds__(256) void k_transpose2(const float* __restrict__ src,
                                                    float* __restrict__ dstF,
                                                    unsigned short* __restrict__ dstB,
                                                    long dstBatch) {
  __shared__ float tile[32][33];
  const float* s = src + (long)blockIdx.z * CH * NT;
  float* dF = dstF + (long)blockIdx.z * dstBatch;
  unsigned short* dB = dstB + (long)blockIdx.z * dstBatch;
  const int m0 = blockIdx.x * 32, c0 = blockIdx.y * 32;
  const int tx = threadIdx.x, ty = threadIdx.y;
#pragma unroll
  for (int i = ty; i < 32; i += 8)
    tile[i][tx] = s[(long)(c0 + i) * NT + (m0 + tx)];
  __syncthreads();
#pragma unroll
  for (int i = ty; i < 32; i += 8) {
    float v = tile[tx][i];
    dF[(long)(m0 + i) * CH + (c0 + tx)] = v;
    unsigned u = __float_as_uint(v);
    dB[(long)(m0 + i) * CH + (c0 + tx)] =
        (unsigned short)((u + 0x7fffu + ((u >> 16) & 1u)) >> 16);  // RNE bf16
  }
}

// ---------------- context squared norms (fp32, coarse ranking only) ----------------
__global__ __launch_bounds__(256) void k_norms(const float* __restrict__ xc1,
                                               const float* __restrict__ xc2,
                                               float* __restrict__ nrm) {
  const int j = blockIdx.x * 256 + threadIdx.x;
  const int b = blockIdx.y;
  const float* src = (j < NT) ? (xc1 + (long)b * CH * NT + j)
                              : (xc2 + (long)b * CH * NT + (j - NT));
  float acc = 0.f;
#pragma unroll 8
  for (int c = 0; c < CH; ++c) {
    float v = src[(long)c * NT];
    acc = fmaf(v, v, acc);
  }
  nrm[(long)b * NCTX + j] = acc;
}

// ---------------- MFMA coarse scorer + per-lane top-CSEL (packed-key min/max bubble) ----------------
// Swapped GEMM: C[ctx(row)][tgt(col)] = Xc . Xt^T via mfma_f32_32x32x16_bf16.
// C/D layout: col = lane&31 (target), row = (reg&3) + 8*(reg>>2) + 4*(lane>>5) (ctx).
// acc initialized with -0.5*nrm_c so score = -2*acc + 512 = d^2 - nrm_t + 512 > 0.
// key = (float_bits(score) & ~0x7FF) | local_ctx_idx. At the end, the two lane-half
// sorted lists are merged via the bitonic split min(A[q], B[CSEL-1-q]) -> top-CSEL
// of the whole split; lh==0 lanes write them (unordered is fine, rescore re-ranks).
__global__ __launch_bounds__(256) void k_dist_mfma(const __bf16* __restrict__ XcB,
                                                   const __bf16* __restrict__ XtB,
                                                   const float* __restrict__ nrm,
                                                   int* __restrict__ cand) {
  __shared__ __bf16 lds[2][32 * CH];   // 2 x 16 KB ctx tiles, fragment-linear order
  __shared__ float nrm_s[CTX_PER];     // 8 KB, holds -0.5*nrm
  const int b = blockIdx.y, split = blockIdx.z;
  const int t = threadIdx.x, w = t >> 6, lane = t & 63;
  const int l31 = lane & 31, lh = lane >> 5;
  const int tgt0 = blockIdx.x * 128 + w * 32;
  const int cbase = split * CTX_PER;

  for (int i = t; i < CTX_PER; i += 256)
    nrm_s[i] = -0.5f * nrm[(long)b * NCTX + cbase + i];

  // B fragments (targets), K=256 in 16 k-steps, register-resident
  const __bf16* tp = XtB + ((long)b * NT + tgt0 + l31) * CH + lh * 8;
  bf16x8 bfrag[16];
#pragma unroll
  for (int s = 0; s < 16; ++s) bfrag[s] = *(const bf16x8*)(tp + s * 16);

  unsigned kd[CSEL];
#pragma unroll
  for (int q = 0; q < CSEL; ++q) kd[q] = 0xFFFFFFFFu;

  const __bf16* cp = XcB + ((long)b * NCTX + cbase + l31) * CH;

  // stage tile jt into lds[buf]: chunk c=(r*4+w)*64+lane holds ctx=lane&31, k8=(r*4+w)*2+(lane>>5)
  // -> LDS linear at (r*4+w)*1024B + lane*16B; ds_read for k-step s is then fully conflict-free.
  auto STAGE = [&](int buf, int jt) {
#pragma unroll
    for (int r = 0; r < 4; ++r) {
      const __bf16* src = cp + (long)jt * 32 * CH + ((r * 4 + w) * 2 + lh) * 8;
      __bf16* dst = &lds[buf][(r * 4 + w) * 512];   // wave-uniform base; HW adds lane*16
      __builtin_amdgcn_global_load_lds((const __attribute__((address_space(1))) void*)src,
                                       (__attribute__((address_space(3))) void*)dst,
                                       16, 0, 0);
    }
  };

  STAGE(0, 0);
  __syncthreads();

  int cur = 0;
  for (int jt = 0; jt < NTILE; ++jt) {
    if (jt + 1 < NTILE) STAGE(cur ^ 1, jt + 1);

    const int ct0 = jt * 32;
    f32x16 acc;
#pragma unroll
    for (int g = 0; g < 4; ++g) {      // acc[4g+j] = -0.5*nrm[ct0 + 8g + 4lh + j]
      float4 nv = *(const float4*)&nrm_s[ct0 + 8 * g + 4 * lh];
      acc[4 * g + 0] = nv.x; acc[4 * g + 1] = nv.y;
      acc[4 * g + 2] = nv.z; acc[4 * g + 3] = nv.w;
    }
#pragma unroll
    for (int s = 0; s < 16; ++s) {
      bf16x8 a = *(const bf16x8*)(&lds[cur][s * 512 + lane * 8]);
      acc = __builtin_amdgcn_mfma_f32_32x32x16_bf16(a, bfrag[s], acc, 0, 0, 0);
    }

#pragma unroll
    for (int reg = 0; reg < 16; ++reg) {
      const int row = (reg & 3) + 8 * (reg >> 2) + lh * 4;
      float sc = fmaf(acc[reg], -2.0f, 512.0f);
      unsigned key = (__float_as_uint(sc) & 0xFFFFF800u) | (unsigned)ct0 | (unsigned)row;
#pragma unroll
      for (int q = 0; q < CSEL; ++q) {   // branchless sorted-ascending bubble insert
        unsigned lo = min(key, kd[q]);
        key = max(key, kd[q]);
        kd[q] = lo;
      }
    }
    __syncthreads();   // drains vmcnt (stage writes) + lgkm; frees read buffer
    cur ^= 1;
  }

  // merge the two lane-half sorted lists: lowest-CSEL of the union = min(A[q], B[CSEL-1-q])
  unsigned oth[CSEL];
#pragma unroll
  for (int q = 0; q < CSEL; ++q) oth[q] = (unsigned)__shfl_xor((int)kd[q], 32, 64);
  if (lh == 0) {
    long ob = (((long)b * NT + tgt0 + l31) * DNSPLIT + split) * CSEL;
#pragma unroll
    for (int q = 0; q < CSEL; ++q) {
      unsigned m = min(kd[q], oth[CSEL - 1 - q]);
      cand[ob + q] = cbase + (int)(m & 0x7FFu);
    }
  }
}

// ---------------- fp64 exact rescore of NCAND candidates -> knn[8] ----------------
// 4 lane-groups of 16; group g rescans candidate q (q%4==g), each lane owns 16 dims.
// Then rank-select: lane q computes exact rank of (d,j) among the 40 and writes knn[rank].
__global__ __launch_bounds__(64) void k_rescore(const float* __restrict__ XtT,
                                                const float* __restrict__ XcT,
                                                const int* __restrict__ cand,
                                                int* __restrict__ knn) {
  const int n = blockIdx.x, b = blockIdx.y, lane = threadIdx.x;
  const int grp = lane >> 4, gl = lane & 15;
  __shared__ double sd[NCAND];
  __shared__ int    sj[NCAND];
  const float* xt = XtT + ((long)b * NT + n) * CH + gl * 16;
  double xa[16];
#pragma unroll
  for (int r = 0; r < 4; ++r) {
    float4 v = *(const float4*)(xt + r * 4);
    xa[4 * r + 0] = (double)v.x; xa[4 * r + 1] = (double)v.y;
    xa[4 * r + 2] = (double)v.z; xa[4 * r + 3] = (double)v.w;
  }
  const int* cd = cand + ((long)b * NT + n) * NCAND;
  for (int q = grp; q < NCAND; q += 4) {
    int j = cd[q];
    const float* xc = XcT + ((long)b * NCTX + j) * CH + gl * 16;
    double acc = 0.0;
#pragma unroll
    for (int r = 0; r < 4; ++r) {
      float4 v = *(const float4*)(xc + r * 4);
      double d0 = xa[4 * r + 0] - (double)v.x; acc = fma(d0, d0, acc);
      double d1 = xa[4 * r + 1] - (double)v.y; acc = fma(d1, d1, acc);
      double d2 = xa[4 * r + 2] - (double)v.z; acc = fma(d2, d2, acc);
      double d3 = xa[4 * r + 3] - (double)v.w; acc = fma(d3, d3, acc);
    }
#pragma unroll
    for (int off = 8; off > 0; off >>= 1) acc += __shfl_xor(acc, off, 64);
    if (gl == 0) { sd[q] = acc; sj[q] = j; }
  }
  __syncthreads();
  double dq = (lane < NCAND) ? sd[lane] : DBL_MAX;
  int    jq = (lane < NCAND) ? sj[lane] : 0x7fffffff;
  int rank = 0;
  for (int i = 0; i < NCAND; ++i) {
    double di = sd[i]; int ji = sj[i];
    rank += (di < dq || (di == dq && ji < jq)) ? 1 : 0;
  }
  if (lane < NCAND && rank < KI)
    knn[((long)b * NT + n) * KI + rank] = jq;
}

// ---------------- counts (segment_sum of ones) ----------------
__global__ __launch_bounds__(256) void k_counts(const int* __restrict__ knn,
                                                unsigned* __restrict__ counts) {
  const int idx = blockIdx.x * 256 + threadIdx.x;   // over BATCH*NT
  const int b = idx >> 12;                          // NT = 4096
  const int* kn = knn + (long)idx * KI;
#pragma unroll
  for (int q = 0; q < KI; ++q) atomicAdd(&counts[(long)b * NCTX + kn[q]], 1u);
}

// ---------------- GEMM + bias: out[M][CH] = A[M][CH] @ W[CH][CH] + b ----------------
#define GTM 64
#define GTN 64
#define GKC 32
__global__ __launch_bounds__(256) void k_gemm_bias(const float* __restrict__ A,
                                                   const float* __restrict__ Wm,
                                                   const float* __restrict__ bias,
                                                   float* __restrict__ out, int M) {
  __shared__ float As[GKC][GTM + 4];
  __shared__ float Bs[GKC][GTN];
  const int b = blockIdx.z;
  const long m0 = (long)blockIdx.x * GTM;
  const int n0 = blockIdx.y * GTN;
  const float* Ab = A + (long)b * M * CH;
  float* ob = out + (long)b * M * CH;
  const int t = threadIdx.x;
  const int tm = (t & 15) * 4;
  const int tn = (t >> 4) * 4;
  float acc[4][4] = {{0.f}};
  for (int kc = 0; kc < CH; kc += GKC) {
    __syncthreads();
#pragma unroll
    for (int rep = 0; rep < 2; ++rep) {
      int p = t + rep * 256;
      int row = p >> 3;
      int ck = (p & 7) * 4;
      float4 va = *(const float4*)(Ab + (m0 + row) * CH + kc + ck);
      As[ck + 0][row] = va.x;
      As[ck + 1][row] = va.y;
      As[ck + 2][row] = va.z;
      As[ck + 3][row] = va.w;
      int rowb = p >> 4;
      int cn = (p & 15) * 4;
      *(float4*)&Bs[rowb][cn] = *(const float4*)(Wm + (long)(kc + rowb) * CH + n0 + cn);
    }
    __syncthreads();
#pragma unroll 8
    for (int k = 0; k < GKC; ++k) {
      float av[4], bv[4];
      *(float4*)av = *(const float4*)&As[k][tm];
      *(float4*)bv = *(const float4*)&Bs[k][tn];
#pragma unroll
      for (int r = 0; r < 4; ++r)
#pragma unroll
        for (int c2 = 0; c2 < 4; ++c2)
          acc[r][c2] = fmaf(av[r], bv[c2], acc[r][c2]);
    }
  }
#pragma unroll
  for (int r = 0; r < 4; ++r) {
    float4 ov;
    ov.x = acc[r][0] + bias[n0 + tn + 0];
    ov.y = acc[r][1] + bias[n0 + tn + 1];
    ov.z = acc[r][2] + bias[n0 + tn + 2];
    ov.w = acc[r][3] + bias[n0 + tn + 3];
    *(float4*)(ob + (m0 + tm + r) * CH + n0 + tn) = ov;
  }
}

// ---------------- gather-mean: X_edge = (Xn_t + sum_k Xn_c[knn]) / 9 ----------------
__global__ __launch_bounds__(256) void k_gather(const float* __restrict__ Xn_t,
                                                const float* __restrict__ Xn_c,
                                                const int* __restrict__ knn,
                                                float* __restrict__ Xe) {
  const int n = blockIdx.x, b = blockIdx.y, c = threadIdx.x;
  const int* kn = knn + ((long)b * NT + n) * KI;
  int j[KI];
#pragma unroll
  for (int q = 0; q < KI; ++q) j[q] = kn[q];
  float acc = Xn_t[((long)b * NT + n) * CH + c];
#pragma unroll
  for (int q = 0; q < KI; ++q) acc += Xn_c[((long)b * NCTX + j[q]) * CH + c];
  Xe[((long)b * NT + n) * CH + c] = acc / 9.0f;
}

// ---------------- scatter-add contributions to context nodes ----------------
__global__ __launch_bounds__(256) void k_scatter(const float* __restrict__ Xet,
                                                 const int* __restrict__ knn,
                                                 float* __restrict__ contrib) {
  const int n = blockIdx.x, b = blockIdx.y, c = threadIdx.x;
  const float v = Xet[((long)b * NT + n) * CH + c];
  const int* kn = knn + ((long)b * NT + n) * KI;
#pragma unroll
  for (int q = 0; q < KI; ++q)
    atomicAdd(&contrib[((long)b * NCTX + kn[q]) * CH + c], v);
}

// ---------------- finalize target output: transpose [NT][CH] -> image [CH][NT] ----------------
__global__ __launch_bounds__(256) void k_fin_t(const float* __restrict__ Xet,
                                               float* __restrict__ out) {
  __shared__ float tile[32][33];
  const int b = blockIdx.z;
  const int n0 = blockIdx.x * 32, c0 = blockIdx.y * 32;
  const int tx = threadIdx.x, ty = threadIdx.y;
#pragma unroll
  for (int i = ty; i < 32; i += 8)
    tile[i][tx] = Xet[((long)b * NT + n0 + i) * CH + c0 + tx];
  __syncthreads();
#pragma unroll
  for (int i = ty; i < 32; i += 8)
    out[((long)b * CH + c0 + i) * NT + n0 + tx] = tile[tx][i];
}

// ---------------- finalize context outputs: divide by counts, transpose, split ----------------
__global__ __launch_bounds__(256) void k_fin_c(const float* __restrict__ contrib,
                                               const unsigned* __restrict__ counts,
                                               float* __restrict__ out1,
                                               float* __restrict__ out2) {
  __shared__ float tile[32][33];
  const int b = blockIdx.z;
  const int j0 = blockIdx.x * 32, c0 = blockIdx.y * 32;
  const int tx = threadIdx.x, ty = threadIdx.y;
#pragma unroll
  for (int i = ty; i < 32; i += 8) {
    float cnt = fmaxf((float)counts[(long)b * NCTX + j0 + i], 1.0f);
    tile[i][tx] = contrib[((long)b * NCTX + j0 + i) * CH + c0 + tx] / cnt;
  }
  __syncthreads();
  float* outp = (j0 < NT) ? (out1 + (long)b * CH * NT + j0)
                          : (out2 + (long)b * CH * NT + (j0 - NT));
#pragma unroll
  for (int i = ty; i < 32; i += 8)
    outp[(long)(c0 + i) * NT + tx] = tile[tx][i];
}

extern "C" void kernel_launch(void* const* d_in, const int* in_sizes, int n_in,
                              void* d_out, int out_size, void* d_ws, size_t ws_size,
                              hipStream_t stream) {
  const float* Xt  = (const float*)d_in[0];
  const float* Xc1 = (const float*)d_in[1];
  const float* Xc2 = (const float*)d_in[2];
  const float* W1  = (const float*)d_in[3];
  const float* b1  = (const float*)d_in[4];
  const float* W2  = (const float*)d_in[5];
  const float* b2  = (const float*)d_in[6];
  float* out = (float*)d_out;

  // ws layout (~65 MB):
  //   P: [BATCH*NCTX*CH]  XcT fp32 -> (after gemm1) contrib
  //   Q: [BATCH*NT*CH]    XtT fp32 -> X_edge
  //   R: [BATCH*NT*CH]    Xn_t -> X_et
  //   nrm, counts, knn
  float* P = (float*)d_ws;
  float* Q = P + (long)BATCH * NCTX * CH;
  float* R = Q + (long)BATCH * NT * CH;
  float* nrm = R + (long)BATCH * NT * CH;
  unsigned* counts = (unsigned*)(nrm + (long)BATCH * NCTX);
  int* knn = (int*)(counts + (long)BATCH * NCTX);

  // d_out (50.3 MB) doubles as scratch until gemm1/finalize overwrite it:
  //   [XcB bf16 16.8MB | XtB bf16 8.4MB | cand 2.6MB]  -- all dead after k_rescore
  unsigned short* XcB = (unsigned short*)d_out;
  unsigned short* XtB = XcB + (long)BATCH * NCTX * CH;
  int* cand = (int*)(XtB + (long)BATCH * NT * CH);

  float* Xn_c  = out;   // written after rescore (scratch region dead by then)
  float* out_t  = out;
  float* out_c1 = out + (long)BATCH * CH * NT;
  float* out_c2 = out + 2L * BATCH * CH * NT;

  dim3 tb(32, 8);

  // node-major fp32 (rescore) + bf16 (MFMA) copies
  k_transpose2<<<dim3(NT / 32, CH / 32, BATCH), tb, 0, stream>>>(Xt,  Q, XtB, (long)NT * CH);
  k_transpose2<<<dim3(NT / 32, CH / 32, BATCH), tb, 0, stream>>>(Xc1, P, XcB, (long)NCTX * CH);
  k_transpose2<<<dim3(NT / 32, CH / 32, BATCH), tb, 0, stream>>>(Xc2, P + (long)NT * CH,
                                                                 XcB + (long)NT * CH,
                                                                 (long)NCTX * CH);

  k_norms<<<dim3(NCTX / 256, BATCH), 256, 0, stream>>>(Xc1, Xc2, nrm);

  // MFMA coarse scoring + merged per-split top-10 -> 40 candidates per target
  k_dist_mfma<<<dim3(NT / 128, BATCH, DNSPLIT), 256, 0, stream>>>(
      (const __bf16*)XcB, (const __bf16*)XtB, nrm, cand);

  // exact fp64 rescore -> knn[8]
  k_rescore<<<dim3(NT, BATCH), 64, 0, stream>>>(Q, P, cand, knn);

  hipMemsetAsync(counts, 0, (size_t)BATCH * NCTX * 4, stream);
  k_counts<<<dim3(BATCH * NT / 256), 256, 0, stream>>>(knn, counts);

  // node2edge linear: Xn_t -> R, Xn_c -> d_out scratch (XcB/XtB/cand dead now)
  k_gemm_bias<<<dim3(NT / GTM, CH / GTN, BATCH), 256, 0, stream>>>(Q, W1, b1, R, NT);
  k_gemm_bias<<<dim3(NCTX / GTM, CH / GTN, BATCH), 256, 0, stream>>>(P, W1, b1, Xn_c, NCTX);

  // edge mean-pool -> Q (XtT dead)
  k_gather<<<dim3(NT, BATCH), 256, 0, stream>>>(R, Xn_c, knn, Q);

  // edge2node linear: X_et -> R (Xn_t dead)
  k_gemm_bias<<<dim3(NT / GTM, CH / GTN, BATCH), 256, 0, stream>>>(Q, W2, b2, R, NT);

  // out_t (overwrites dead Xn_c region of d_out)
  k_fin_t<<<dim3(NT / 32, CH / 32, BATCH), tb, 0, stream>>>(R, out_t);

  // context scatter-mean (P = XcT dead -> contrib)
  hipMemsetAsync(P, 0, (size_t)BATCH * NCTX * CH * 4, stream);
  k_scatter<<<dim3(NT, BATCH), 256, 0, stream>>>(R, knn, P);
  k_fin_c<<<dim3(NCTX / 32, CH / 32, BATCH), tb, 0, stream>>>(P, counts, out_c1, out_c2);
}